// Round 4
// baseline (492.030 us; speedup 1.0000x reference)
//
#include <hip/hip_runtime.h>
#include <hip/hip_bf16.h>

// VQ-VAE vector quantizer, MI355X. z:(16,512,64,64) f32, codebook:(1024,512) f32.
// d_out f32: z_q (33554432), loss (1), idx (65536).

typedef _Float16 h8 __attribute__((ext_vector_type(8)));
typedef float f32x16 __attribute__((ext_vector_type(16)));

#define OUT_LOSS  33554432
#define OUT_IDX   33554433
#define MARGIN_T  0.15f     // ~9 sigma of fp16-dot noise on the t-gap

__device__ __forceinline__ void gload_lds16(const void* g, void* l) {
  __builtin_amdgcn_global_load_lds(
      (const __attribute__((address_space(1))) void*)g,
      (__attribute__((address_space(3))) void*)l, 16, 0, 0);
}

// ---- K0: cb fp32->fp16, fold-ordered 0.5||c||^2 table, workspace init ---------
__global__ __launch_bounds__(64) void k0_prep(
    const float* __restrict__ cb, unsigned short* __restrict__ cb16,
    float* __restrict__ cnp, int* __restrict__ flagcount, float* __restrict__ loss_acc,
    int* __restrict__ idx_ws, unsigned long long* __restrict__ packed_ws)
{
  const int r = blockIdx.x, l = threadIdx.x;
  const float* row = cb + (size_t)r * 512;
  float4 a  = *(const float4*)(row + l * 8);
  float4 b4 = *(const float4*)(row + l * 8 + 4);
  h8 hv;
  hv[0] = (_Float16)a.x;  hv[1] = (_Float16)a.y;  hv[2] = (_Float16)a.z;  hv[3] = (_Float16)a.w;
  hv[4] = (_Float16)b4.x; hv[5] = (_Float16)b4.y; hv[6] = (_Float16)b4.z; hv[7] = (_Float16)b4.w;
  *reinterpret_cast<h8*>(cb16 + (size_t)r * 512 + l * 8) = hv;
  float s = a.x*a.x + a.y*a.y + a.z*a.z + a.w*a.w
          + b4.x*b4.x + b4.y*b4.y + b4.z*b4.z + b4.w*b4.w;
  #pragma unroll
  for (int off = 1; off < 64; off <<= 1) s += __shfl_xor(s, off);
  if (l == 0) {
    // store 0.5*||c||^2 at the fold-order slot: [ch][khalf][r]
    int jr = r & 31, ch = r >> 5;
    int khalf = (jr >> 2) & 1;
    int pat = jr - (khalf << 2);               // in {0-3,8-11,16-19,24-27}
    int rr  = (pat & 3) + ((pat >> 3) << 2);   // 0..15
    cnp[(ch << 5) + (khalf << 4) + rr] = 0.5f * s;
  }
  const int pix = (r << 6) + l;                // 1024x64 == 65536
  idx_ws[pix] = (int)0x80000000;
  packed_ws[pix] = ~0ull;
  if (r == 0 && l == 0) { *flagcount = 0; *loss_acc = 0.f; }
}

// ---- K1: fp16 MFMA scan, 8 waves, triple-buffer + counted vmcnt ---------------
// 512 thr, 256 px/block, 256 blocks (1/CU). dynLDS = 3*32768 + 4096 = 102400.
// Chunk buffer layout (transposed): LDS off = m*512 + row*16 (+e*2), where
// m = 2*s + khalf selects 8 consecutive channels, row = cb row within chunk.
// => A-read for (row=pxl, k-slot s, khalf): base(pxl*16 + khalf*512) + s*1024. 
//    Wave reads contiguous 1KB -> 0 bank conflicts, imm-offset addressing.
__global__ __launch_bounds__(512, 2) void k1_main(
    const float* __restrict__ z, const unsigned short* __restrict__ cb16,
    const float* __restrict__ cnp,
    int* __restrict__ idx_ws, int* __restrict__ flaglist, int* __restrict__ flagcount)
{
  extern __shared__ char smem[];
  float* cn_lds = reinterpret_cast<float*>(smem + 98304);
  const int tid   = threadIdx.x;
  const int lane  = tid & 63;
  const int wave  = tid >> 6;          // 0..7
  const int pxl   = lane & 31;
  const int khalf = lane >> 5;
  const int px0   = blockIdx.x << 8;   // 256 px/block
  const int b     = px0 >> 12;
  const int hw0   = px0 & 4095;
  // pre-swizzled source: lane L reads cb16 row (L&31), channel-block (slab*2 + L>>5)
  const int laneoff = pxl * 1024 + khalf * 16;   // bytes within a 32-row chunk

  // prologue: stage chunk 0 into buf0 (transposed via source swizzle)
  {
    const char* src = reinterpret_cast<const char*>(cb16) + laneoff;
    #pragma unroll
    for (int i = 0; i < 4; ++i) {
      int slab = (wave << 2) + i;      // 0..31
      gload_lds16(src + slab * 32, smem + slab * 1024);
    }
  }

  // B-fragments straight from global: 32 px/wave x K=512 fp16 in VGPRs
  h8 bfrag[32];
  {
    const float* zl = z + ((size_t)(b * 512 + khalf * 8)) * 4096 + hw0 + (wave << 5) + pxl;
    #pragma unroll
    for (int s = 0; s < 32; ++s) {
      const float* zs = zl + (size_t)s * 16 * 4096;
      h8 hv;
      #pragma unroll
      for (int e = 0; e < 8; ++e) hv[e] = (_Float16)zs[(size_t)e * 4096];
      bfrag[s] = hv;
    }
  }
  for (int i = tid; i < 1024; i += 512) cn_lds[i] = cnp[i];
  __syncthreads();   // prologue drain (pf0 landed long ago)

  float v0r = INFINITY, v1r = INFINITY;
  int   i0r = 0;

  for (int ch = 0; ch < 32; ++ch) {
    const char* cbuf = smem + (ch % 3) * 32768;
    if (ch < 31) {
      char* dbuf = smem + ((ch + 1) % 3) * 32768;
      const char* src = reinterpret_cast<const char*>(cb16) + ((ch + 1) << 15) + laneoff;
      #pragma unroll
      for (int i = 0; i < 4; ++i) {
        int slab = (wave << 2) + i;
        gload_lds16(src + slab * 32, dbuf + slab * 1024);
      }
      asm volatile("s_waitcnt vmcnt(4)" ::: "memory");  // own chunk-ch loads done
    } else {
      asm volatile("s_waitcnt vmcnt(0)" ::: "memory");
    }
    __builtin_amdgcn_s_barrier();      // all waves' chunk-ch staging visible

    f32x16 acca, accb;
    #pragma unroll
    for (int i = 0; i < 16; ++i) { acca[i] = 0.f; accb[i] = 0.f; }
    {
      const char* ab = cbuf + (pxl << 4) + (khalf << 9);
      #pragma unroll
      for (int s = 0; s < 16; ++s) {
        h8 a0 = *reinterpret_cast<const h8*>(ab + (s << 10));
        h8 a1 = *reinterpret_cast<const h8*>(ab + ((s + 16) << 10));
        acca = __builtin_amdgcn_mfma_f32_32x32x16_f16(a0, bfrag[s],      acca, 0, 0, 0);
        accb = __builtin_amdgcn_mfma_f32_32x32x16_f16(a1, bfrag[s + 16], accb, 0, 0, 0);
      }
    }
    const float* cl = cn_lds + (ch << 5) + (khalf << 4);
    float4 q0 = *(const float4*)(cl);     float4 q1 = *(const float4*)(cl + 4);
    float4 q2 = *(const float4*)(cl + 8); float4 q3 = *(const float4*)(cl + 12);
    const float cn[16] = {q0.x,q0.y,q0.z,q0.w, q1.x,q1.y,q1.z,q1.w,
                          q2.x,q2.y,q2.z,q2.w, q3.x,q3.y,q3.z,q3.w};
    const int jbase = (ch << 5) + (khalf << 2);
    #pragma unroll
    for (int r = 0; r < 16; ++r) {
      int j = jbase + ((r & 3) + ((r >> 2) << 3));
      float sc = cn[r] - (acca[r] + accb[r]);   // 0.5||c||^2 - z.c
      bool better = (sc < v0r) || (sc == v0r && j < i0r);
      v1r = better ? v0r : fminf(v1r, sc);
      if (better) { v0r = sc; i0r = j; }
    }
  }

  // merge khalf halves (pixel p state in lanes p and p+32)
  {
    float ov0 = __shfl_xor(v0r, 32);
    float ov1 = __shfl_xor(v1r, 32);
    int   oi0 = __shfl_xor(i0r, 32);
    bool take = (ov0 < v0r) || (ov0 == v0r && oi0 < i0r);
    float loser = take ? v0r : ov0;
    v1r = fminf(fminf(v1r, ov1), loser);
    if (take) { v0r = ov0; i0r = oi0; }
  }

  if (lane < 32) {
    const int pix = px0 + (wave << 5) + lane;
    bool ok   = (v1r - v0r >= MARGIN_T) && ((unsigned)i0r < 1024u);
    bool flag = !ok;
    idx_ws[pix] = flag ? (int)0x80000000 : i0r;
    unsigned long long mask = __ballot(flag);
    if (mask) {
      int leader = __ffsll((unsigned long long)mask) - 1;
      int basev = 0;
      if (lane == leader) basev = atomicAdd(flagcount, __popcll(mask));
      basev = __shfl(basev, leader);
      if (flag) {
        int pos = __popcll(mask & ((1ull << lane) - 1ull));
        flaglist[basev + pos] = pix;
      }
    }
  }
}

// ---- K2: exact fp64 re-rank of flagged pixels ---------------------------------
__global__ __launch_bounds__(256) void k2_rescan(
    const float* __restrict__ z, const float* __restrict__ cb,
    const int* __restrict__ flaglist, const int* __restrict__ flagcount,
    unsigned long long* __restrict__ packed_ws)
{
  __shared__ float zb[16][512];
  __shared__ unsigned long long best[16];
  __shared__ int pixl[16];
  const int t = threadIdx.x;
  const int nflag = *flagcount;
  const int ntasks = ((nflag + 15) >> 4) << 2;
  for (int task = blockIdx.x; task < ntasks; task += gridDim.x) {
    const int g = task >> 2, q = task & 3;
    int rem = nflag - (g << 4);
    const int npx = rem < 16 ? rem : 16;
    if (t < 16) {
      best[t] = ~0ull;
      pixl[t] = (t < npx) ? flaglist[(g << 4) + t] : 0;
    }
    __syncthreads();
    for (int i = t; i < (npx << 9); i += 256) {
      int p = i >> 9, c = i & 511;
      int pix = pixl[p];
      zb[p][c] = z[((size_t)(pix >> 12) * 512 + c) * 4096 + (pix & 4095)];
    }
    __syncthreads();
    const int j = (q << 8) + t;
    const float* row = cb + (size_t)j * 512;
    double dot[16];
    #pragma unroll
    for (int p = 0; p < 16; ++p) dot[p] = 0.0;
    double cn = 0.0;
    for (int k = 0; k < 512; k += 4) {
      float4 cv = *(const float4*)(row + k);
      double c0 = cv.x, c1 = cv.y, c2 = cv.z, c3 = cv.w;
      cn = fma(c0, c0, cn); cn = fma(c1, c1, cn);
      cn = fma(c2, c2, cn); cn = fma(c3, c3, cn);
      #pragma unroll
      for (int p = 0; p < 16; ++p) {
        dot[p] = fma(c0, (double)zb[p][k + 0], dot[p]);
        dot[p] = fma(c1, (double)zb[p][k + 1], dot[p]);
        dot[p] = fma(c2, (double)zb[p][k + 2], dot[p]);
        dot[p] = fma(c3, (double)zb[p][k + 3], dot[p]);
      }
    }
    #pragma unroll
    for (int p = 0; p < 16; ++p) {
      if (p < npx) {
        double d = fma(-2.0, dot[p], cn);
        unsigned long long u = (unsigned long long)__double_as_longlong(d);
        u = (u >> 63) ? ~u : (u | 0x8000000000000000ull);
        unsigned long long pk = (u & ~1023ull) | (unsigned long long)j;
        atomicMin(&best[p], pk);
      }
    }
    __syncthreads();
    if (t < npx) atomicMin(&packed_ws[pixl[t]], best[t]);
    __syncthreads();
  }
}

// ---- K3: gather + transpose-write z_q (f32), idx (f32), loss ------------------
// 32 px/block, 2048 blocks, dynamic LDS 32*513*4 = 65664.
__global__ __launch_bounds__(256) void k3_out(
    const float* __restrict__ z, const float* __restrict__ cb,
    const int* __restrict__ idx_ws, const unsigned long long* __restrict__ packed_ws,
    float* __restrict__ out, float* __restrict__ loss_acc)
{
  extern __shared__ float rows[];         // [32][513]
  __shared__ int idxs[32];
  __shared__ float wsum[4];
  const int t = threadIdx.x;
  const int pix0 = blockIdx.x << 5;       // 32 px/block
  const int b = pix0 >> 12, hw0 = pix0 & 4095;
  if (t < 32) {
    int pix = pix0 + t;
    int v = idx_ws[pix];
    unsigned j = (v < 0) ? (unsigned)(packed_ws[pix] & 1023ull) : (unsigned)v;
    j &= 1023u;
    idxs[t] = (int)j;
    out[OUT_IDX + pix] = (float)j;
  }
  __syncthreads();
  for (int i = t; i < 32 * 128; i += 256) {
    int r = i >> 7, kq = (i & 127) << 2;
    float4 v = *(const float4*)(cb + (size_t)idxs[r] * 512 + kq);
    float* dst = rows + r * 513 + kq;
    dst[0] = v.x; dst[1] = v.y; dst[2] = v.z; dst[3] = v.w;
  }
  __syncthreads();
  const int pl = (t & 7) << 2;   // pixel quad {0,4,...,28}
  const int cg = t >> 3;         // 0..31
  float acc = 0.f;
  for (int c0 = 0; c0 < 512; c0 += 32) {
    int c = c0 + cg;
    size_t go = ((size_t)(b * 512 + c)) * 4096 + hw0 + pl;
    float4 zv = *(const float4*)(z + go);
    float q0 = rows[(pl + 0) * 513 + c], q1 = rows[(pl + 1) * 513 + c];
    float q2 = rows[(pl + 2) * 513 + c], q3 = rows[(pl + 3) * 513 + c];
    float d0 = q0 - zv.x, d1 = q1 - zv.y, d2 = q2 - zv.z, d3 = q3 - zv.w;
    acc = fmaf(d0, d0, acc); acc = fmaf(d1, d1, acc);
    acc = fmaf(d2, d2, acc); acc = fmaf(d3, d3, acc);
    float4 qv;
    qv.x = zv.x + d0; qv.y = zv.y + d1;    // mimic ref: zp + (z_q - zp)
    qv.z = zv.z + d2; qv.w = zv.w + d3;
    *reinterpret_cast<float4*>(out + go) = qv;
  }
  #pragma unroll
  for (int off = 32; off > 0; off >>= 1) acc += __shfl_down(acc, off);
  if ((t & 63) == 0) wsum[t >> 6] = acc;
  __syncthreads();
  if (t == 0) atomicAdd(loss_acc, wsum[0] + wsum[1] + wsum[2] + wsum[3]);
}

__global__ void k4_loss(const float* __restrict__ loss_acc, float* __restrict__ out)
{
  if (threadIdx.x == 0 && blockIdx.x == 0)
    out[OUT_LOSS] = loss_acc[0] * (1.25f / 33554432.f);
}

// ---- launch --------------------------------------------------------------------
extern "C" void kernel_launch(void* const* d_in, const int* in_sizes, int n_in,
                              void* d_out, int out_size, void* d_ws, size_t ws_size,
                              hipStream_t stream) {
  const float* z  = (const float*)d_in[0];
  const float* cb = (const float*)d_in[1];
  float* out = (float*)d_out;
  char* ws = (char*)d_ws;
  unsigned short*      cb16      = (unsigned short*)(ws);                 // 1 MB
  float*               cnp       = (float*)(ws + 1048576);                // 4 KB
  int*                 idx_ws    = (int*)(ws + 1052672);                  // 256 KB
  unsigned long long*  packed_ws = (unsigned long long*)(ws + 1314816);   // 512 KB
  int*                 flaglist  = (int*)(ws + 1839104);                  // 256 KB
  int*                 flagcount = (int*)(ws + 2101248);
  float*               loss_acc  = (float*)(ws + 2101252);

  (void)hipFuncSetAttribute((const void*)k1_main,
        hipFuncAttributeMaxDynamicSharedMemorySize, 102400);
  (void)hipFuncSetAttribute((const void*)k3_out,
        hipFuncAttributeMaxDynamicSharedMemorySize, 65664);

  k0_prep<<<1024, 64, 0, stream>>>(cb, cb16, cnp, flagcount, loss_acc, idx_ws, packed_ws);
  k1_main<<<256, 512, 102400, stream>>>(z, cb16, cnp, idx_ws, flaglist, flagcount);
  k2_rescan<<<256, 256, 0, stream>>>(z, cb, flaglist, flagcount, packed_ws);
  k3_out<<<2048, 256, 65664, stream>>>(z, cb, idx_ws, packed_ws, out, loss_acc);
  k4_loss<<<1, 1, 0, stream>>>(loss_acc, out);
}

// Round 5
// 348.361 us; speedup vs baseline: 1.4124x; 1.4124x over previous
//
#include <hip/hip_runtime.h>
#include <hip/hip_bf16.h>

// VQ-VAE vector quantizer, MI355X. z:(16,512,64,64) f32, codebook:(1024,512) f32.
// d_out f32: z_q (33554432), loss (1), idx (65536).

typedef _Float16 h8 __attribute__((ext_vector_type(8)));
typedef float f32x16 __attribute__((ext_vector_type(16)));

#define OUT_LOSS  33554432
#define OUT_IDX   33554433
#define MARGIN_T  0.15f     // ~13 sigma of fp16-dot noise on the t-gap

__device__ __forceinline__ void gload_lds16(const void* g, void* l) {
  __builtin_amdgcn_global_load_lds(
      (const __attribute__((address_space(1))) void*)g,
      (__attribute__((address_space(3))) void*)l, 16, 0, 0);
}

// ---- K0: cb fp32->fp16, fold-ordered 0.5||c||^2 table, workspace init ---------
__global__ __launch_bounds__(64) void k0_prep(
    const float* __restrict__ cb, unsigned short* __restrict__ cb16,
    float* __restrict__ cnp, int* __restrict__ counters, float* __restrict__ loss_acc,
    int* __restrict__ idx_ws, unsigned long long* __restrict__ packed_ws)
{
  const int r = blockIdx.x, l = threadIdx.x;
  const float* row = cb + (size_t)r * 512;
  float4 a  = *(const float4*)(row + l * 8);
  float4 b4 = *(const float4*)(row + l * 8 + 4);
  h8 hv;
  hv[0] = (_Float16)a.x;  hv[1] = (_Float16)a.y;  hv[2] = (_Float16)a.z;  hv[3] = (_Float16)a.w;
  hv[4] = (_Float16)b4.x; hv[5] = (_Float16)b4.y; hv[6] = (_Float16)b4.z; hv[7] = (_Float16)b4.w;
  *reinterpret_cast<h8*>(cb16 + (size_t)r * 512 + l * 8) = hv;
  float s = a.x*a.x + a.y*a.y + a.z*a.z + a.w*a.w
          + b4.x*b4.x + b4.y*b4.y + b4.z*b4.z + b4.w*b4.w;
  #pragma unroll
  for (int off = 1; off < 64; off <<= 1) s += __shfl_xor(s, off);
  if (l == 0) {
    // store 0.5*||c||^2 at the fold-order slot: [ch][khalf][reg]
    int jr = r & 31, ch = r >> 5;
    int khalf = (jr >> 2) & 1;
    int pat = jr - (khalf << 2);
    int rr  = (pat & 3) + ((pat >> 3) << 2);
    cnp[(ch << 5) + (khalf << 4) + rr] = 0.5f * s;
  }
  const int pix = (r << 6) + l;                // 1024x64 == 65536
  idx_ws[pix] = (int)0x80000000;
  packed_ws[pix] = ~0ull;
  if (r == 0 && l == 0) { counters[0] = 0; counters[1] = 0; *loss_acc = 0.f; }
}

// ---- K1: fp16 MFMA scan, 8 waves, triple-buffer + counted vmcnt, top-4 --------
// 512 thr, 256 px/block, 256 blocks (1/CU). dynLDS = 3*32768 + 4096 = 102400.
__global__ __launch_bounds__(512, 2) void k1_main(
    const float* __restrict__ z, const unsigned short* __restrict__ cb16,
    const float* __restrict__ cnp,
    int* __restrict__ idx_ws, int* __restrict__ flaglist,
    unsigned long long* __restrict__ pairlist, int* __restrict__ counters)
{
  extern __shared__ char smem[];
  float* cn_lds = reinterpret_cast<float*>(smem + 98304);
  const int tid   = threadIdx.x;
  const int lane  = tid & 63;
  const int wave  = tid >> 6;          // 0..7
  const int pxl   = lane & 31;
  const int khalf = lane >> 5;
  const int px0   = blockIdx.x << 8;   // 256 px/block
  const int b     = px0 >> 12;
  const int hw0   = px0 & 4095;
  const int laneoff = pxl * 1024 + khalf * 16;   // bytes within a 32-row chunk

  // prologue: stage chunk 0 into buf0 (transposed via source swizzle)
  {
    const char* src = reinterpret_cast<const char*>(cb16) + laneoff;
    #pragma unroll
    for (int i = 0; i < 4; ++i) {
      int slab = (wave << 2) + i;
      gload_lds16(src + slab * 32, smem + slab * 1024);
    }
  }

  // B-fragments straight from global: 32 px/wave x K=512 fp16 in VGPRs
  h8 bfrag[32];
  {
    const float* zl = z + ((size_t)(b * 512 + khalf * 8)) * 4096 + hw0 + (wave << 5) + pxl;
    #pragma unroll
    for (int s = 0; s < 32; ++s) {
      const float* zs = zl + (size_t)s * 16 * 4096;
      h8 hv;
      #pragma unroll
      for (int e = 0; e < 8; ++e) hv[e] = (_Float16)zs[(size_t)e * 4096];
      bfrag[s] = hv;
    }
  }
  for (int i = tid; i < 1024; i += 512) cn_lds[i] = cnp[i];
  __syncthreads();   // prologue drain

  float v0 = INFINITY, v1 = INFINITY, v2 = INFINITY, v3 = INFINITY;
  int   i0 = 0, i1 = 0, i2 = 0, i3 = 0;

  for (int ch = 0; ch < 32; ++ch) {
    const char* cbuf = smem + (ch % 3) * 32768;
    if (ch < 31) {
      char* dbuf = smem + ((ch + 1) % 3) * 32768;
      const char* src = reinterpret_cast<const char*>(cb16) + ((ch + 1) << 15) + laneoff;
      #pragma unroll
      for (int i = 0; i < 4; ++i) {
        int slab = (wave << 2) + i;
        gload_lds16(src + slab * 32, dbuf + slab * 1024);
      }
      asm volatile("s_waitcnt vmcnt(4)" ::: "memory");
    } else {
      asm volatile("s_waitcnt vmcnt(0)" ::: "memory");
    }
    __builtin_amdgcn_s_barrier();

    f32x16 acca, accb;
    #pragma unroll
    for (int i = 0; i < 16; ++i) { acca[i] = 0.f; accb[i] = 0.f; }
    {
      const char* ab = cbuf + (pxl << 4) + (khalf << 9);
      #pragma unroll
      for (int s = 0; s < 16; ++s) {
        h8 a0 = *reinterpret_cast<const h8*>(ab + (s << 10));
        h8 a1 = *reinterpret_cast<const h8*>(ab + ((s + 16) << 10));
        acca = __builtin_amdgcn_mfma_f32_32x32x16_f16(a0, bfrag[s],      acca, 0, 0, 0);
        accb = __builtin_amdgcn_mfma_f32_32x32x16_f16(a1, bfrag[s + 16], accb, 0, 0, 0);
      }
    }
    const float* cl = cn_lds + (ch << 5) + (khalf << 4);
    float4 q0 = *(const float4*)(cl);     float4 q1 = *(const float4*)(cl + 4);
    float4 q2 = *(const float4*)(cl + 8); float4 q3 = *(const float4*)(cl + 12);
    const float cn[16] = {q0.x,q0.y,q0.z,q0.w, q1.x,q1.y,q1.z,q1.w,
                          q2.x,q2.y,q2.z,q2.w, q3.x,q3.y,q3.z,q3.w};
    const int jbase = (ch << 5) + (khalf << 2);
    #pragma unroll
    for (int r = 0; r < 16; ++r) {
      int j = jbase + ((r & 3) + ((r >> 2) << 3));
      float sc = cn[r] - (acca[r] + accb[r]);   // 0.5||c||^2 - z.c
      if (sc <= v3) {            // top-4 insert (ties at boundary droppable: safe)
        if (sc < v0)      { v3=v2;i3=i2; v2=v1;i2=i1; v1=v0;i1=i0; v0=sc;i0=j; }
        else if (sc < v1) { v3=v2;i3=i2; v2=v1;i2=i1; v1=sc;i1=j; }
        else if (sc < v2) { v3=v2;i3=i2; v2=sc;i2=j; }
        else              { v3=sc;i3=j; }
      }
    }
  }

  // merge khalf halves (disjoint code sets; lanes p and p+32 both merge)
  #pragma unroll
  for (int k = 0; k < 4; ++k) {
    float ov = __shfl_xor(k == 0 ? v0 : (k == 1 ? v1 : (k == 2 ? v2 : v3)), 32);
    int   oi = __shfl_xor(k == 0 ? i0 : (k == 1 ? i1 : (k == 2 ? i2 : i3)), 32);
    if (ov <= v3) {
      if (ov < v0)      { v3=v2;i3=i2; v2=v1;i2=i1; v1=v0;i1=i0; v0=ov;i0=oi; }
      else if (ov < v1) { v3=v2;i3=i2; v2=v1;i2=i1; v1=ov;i1=oi; }
      else if (ov < v2) { v3=v2;i3=i2; v2=ov;i2=oi; }
      else              { v3=ov;i3=oi; }
    }
  }

  const int pix = px0 + (wave << 5) + lane;   // valid for lane<32 only
  bool sane = (v0 == v0) && (v3 == v3) && ((unsigned)i0 < 1024u);
  bool unfl = sane && (v1 - v0 >= MARGIN_T);
  bool quad = sane && !unfl && (v3 - v0 >= MARGIN_T);
  bool qpred = (lane < 32) && quad;
  bool fpred = (lane < 32) && !unfl && !quad;
  if (lane < 32) idx_ws[pix] = unfl ? i0 : (int)0x80000000;

  unsigned long long qm = __ballot(qpred);
  if (qm) {
    int leader = __ffsll(qm) - 1;
    int base = 0;
    if (lane == leader) base = atomicAdd(&counters[1], __popcll(qm));
    base = __shfl(base, leader);
    if (qpred) {
      int pos = __popcll(qm & ((1ull << lane) - 1ull));
      pairlist[base + pos] = (unsigned long long)(unsigned)pix
          | ((unsigned long long)(unsigned)i0 << 16)
          | ((unsigned long long)(unsigned)i1 << 26)
          | ((unsigned long long)(unsigned)i2 << 36)
          | ((unsigned long long)(unsigned)i3 << 46);
    }
  }
  unsigned long long fm = __ballot(fpred);
  if (fm) {
    int leader = __ffsll(fm) - 1;
    int base = 0;
    if (lane == leader) base = atomicAdd(&counters[0], __popcll(fm));
    base = __shfl(base, leader);
    if (fpred) {
      int pos = __popcll(fm & ((1ull << lane) - 1ull));
      flaglist[base + pos] = pix;
    }
  }
}

// ---- K2a: exact fp64 check of <=4 candidates, one wave per pixel --------------
__global__ __launch_bounds__(256) void k2a_quad(
    const float* __restrict__ z, const float* __restrict__ cb,
    const unsigned long long* __restrict__ pairlist, const int* __restrict__ counters,
    int* __restrict__ idx_ws)
{
  const int lane = threadIdx.x & 63;
  const int wid  = (blockIdx.x << 2) + (threadIdx.x >> 6);
  const int nwav = gridDim.x << 2;
  const int nf   = counters[1];
  for (int e = wid; e < nf; e += nwav) {
    unsigned long long pk = pairlist[e];
    int pix = (int)(pk & 0xFFFFull);
    int c0 = (int)((pk >> 16) & 1023ull), c1 = (int)((pk >> 26) & 1023ull);
    int c2 = (int)((pk >> 36) & 1023ull), c3 = (int)((pk >> 46) & 1023ull);
    const float* zp = z + (size_t)(pix >> 12) * 512 * 4096 + (pix & 4095);
    double s0 = 0, s1 = 0, s2 = 0, s3 = 0;
    #pragma unroll
    for (int k = 0; k < 8; ++k) {
      int c = lane + (k << 6);
      double zv2 = 2.0 * (double)zp[(size_t)c * 4096];
      double a;
      a = (double)cb[(size_t)c0 * 512 + c]; s0 = fma(a, a - zv2, s0);
      a = (double)cb[(size_t)c1 * 512 + c]; s1 = fma(a, a - zv2, s1);
      a = (double)cb[(size_t)c2 * 512 + c]; s2 = fma(a, a - zv2, s2);
      a = (double)cb[(size_t)c3 * 512 + c]; s3 = fma(a, a - zv2, s3);
    }
    #pragma unroll
    for (int off = 32; off > 0; off >>= 1) {
      s0 += __shfl_xor(s0, off); s1 += __shfl_xor(s1, off);
      s2 += __shfl_xor(s2, off); s3 += __shfl_xor(s3, off);
    }
    double bv = s0; int bi = c0;
    if (s1 < bv || (s1 == bv && c1 < bi)) { bv = s1; bi = c1; }
    if (s2 < bv || (s2 == bv && c2 < bi)) { bv = s2; bi = c2; }
    if (s3 < bv || (s3 == bv && c3 < bi)) { bv = s3; bi = c3; }
    if (lane == 0) idx_ws[pix] = bi;
  }
}

// ---- K2b: exact fp64 full re-rank (rare: >=4 codes within margin) -------------
__global__ __launch_bounds__(256) void k2_rescan(
    const float* __restrict__ z, const float* __restrict__ cb,
    const int* __restrict__ flaglist, const int* __restrict__ counters,
    unsigned long long* __restrict__ packed_ws)
{
  __shared__ float zb[16][512];
  __shared__ unsigned long long best[16];
  __shared__ int pixl[16];
  const int t = threadIdx.x;
  const int nflag = counters[0];
  const int ntasks = ((nflag + 15) >> 4) << 2;
  for (int task = blockIdx.x; task < ntasks; task += gridDim.x) {
    const int g = task >> 2, q = task & 3;
    int rem = nflag - (g << 4);
    const int npx = rem < 16 ? rem : 16;
    if (t < 16) {
      best[t] = ~0ull;
      pixl[t] = (t < npx) ? flaglist[(g << 4) + t] : 0;
    }
    __syncthreads();
    for (int i = t; i < (npx << 9); i += 256) {
      int p = i >> 9, c = i & 511;
      int pix = pixl[p];
      zb[p][c] = z[((size_t)(pix >> 12) * 512 + c) * 4096 + (pix & 4095)];
    }
    __syncthreads();
    const int j = (q << 8) + t;
    const float* row = cb + (size_t)j * 512;
    double dot[16];
    #pragma unroll
    for (int p = 0; p < 16; ++p) dot[p] = 0.0;
    double cn = 0.0;
    for (int k = 0; k < 512; k += 4) {
      float4 cv = *(const float4*)(row + k);
      double c0 = cv.x, c1 = cv.y, c2 = cv.z, c3 = cv.w;
      cn = fma(c0, c0, cn); cn = fma(c1, c1, cn);
      cn = fma(c2, c2, cn); cn = fma(c3, c3, cn);
      #pragma unroll
      for (int p = 0; p < 16; ++p) {
        dot[p] = fma(c0, (double)zb[p][k + 0], dot[p]);
        dot[p] = fma(c1, (double)zb[p][k + 1], dot[p]);
        dot[p] = fma(c2, (double)zb[p][k + 2], dot[p]);
        dot[p] = fma(c3, (double)zb[p][k + 3], dot[p]);
      }
    }
    #pragma unroll
    for (int p = 0; p < 16; ++p) {
      if (p < npx) {
        double d = fma(-2.0, dot[p], cn);
        unsigned long long u = (unsigned long long)__double_as_longlong(d);
        u = (u >> 63) ? ~u : (u | 0x8000000000000000ull);
        unsigned long long pkk = (u & ~1023ull) | (unsigned long long)j;
        atomicMin(&best[p], pkk);
      }
    }
    __syncthreads();
    if (t < npx) atomicMin(&packed_ws[pixl[t]], best[t]);
    __syncthreads();
  }
}

// ---- K3: gather + transpose-write z_q (f32), idx (f32), loss ------------------
__global__ __launch_bounds__(256) void k3_out(
    const float* __restrict__ z, const float* __restrict__ cb,
    const int* __restrict__ idx_ws, const unsigned long long* __restrict__ packed_ws,
    float* __restrict__ out, float* __restrict__ loss_acc)
{
  extern __shared__ float rows[];         // [32][513]
  __shared__ int idxs[32];
  __shared__ float wsum[4];
  const int t = threadIdx.x;
  const int pix0 = blockIdx.x << 5;       // 32 px/block
  const int b = pix0 >> 12, hw0 = pix0 & 4095;
  if (t < 32) {
    int pix = pix0 + t;
    int v = idx_ws[pix];
    unsigned j = (v < 0) ? (unsigned)(packed_ws[pix] & 1023ull) : (unsigned)v;
    j &= 1023u;
    idxs[t] = (int)j;
    out[OUT_IDX + pix] = (float)j;
  }
  __syncthreads();
  for (int i = t; i < 32 * 128; i += 256) {
    int r = i >> 7, kq = (i & 127) << 2;
    float4 v = *(const float4*)(cb + (size_t)idxs[r] * 512 + kq);
    float* dst = rows + r * 513 + kq;
    dst[0] = v.x; dst[1] = v.y; dst[2] = v.z; dst[3] = v.w;
  }
  __syncthreads();
  const int pl = (t & 7) << 2;   // pixel quad {0,4,...,28}
  const int cg = t >> 3;         // 0..31
  float acc = 0.f;
  for (int c0 = 0; c0 < 512; c0 += 32) {
    int c = c0 + cg;
    size_t go = ((size_t)(b * 512 + c)) * 4096 + hw0 + pl;
    float4 zv = *(const float4*)(z + go);
    float q0 = rows[(pl + 0) * 513 + c], q1 = rows[(pl + 1) * 513 + c];
    float q2 = rows[(pl + 2) * 513 + c], q3 = rows[(pl + 3) * 513 + c];
    float d0 = q0 - zv.x, d1 = q1 - zv.y, d2 = q2 - zv.z, d3 = q3 - zv.w;
    acc = fmaf(d0, d0, acc); acc = fmaf(d1, d1, acc);
    acc = fmaf(d2, d2, acc); acc = fmaf(d3, d3, acc);
    float4 qv;
    qv.x = zv.x + d0; qv.y = zv.y + d1;    // mimic ref: zp + (z_q - zp)
    qv.z = zv.z + d2; qv.w = zv.w + d3;
    *reinterpret_cast<float4*>(out + go) = qv;
  }
  #pragma unroll
  for (int off = 32; off > 0; off >>= 1) acc += __shfl_down(acc, off);
  if ((t & 63) == 0) wsum[t >> 6] = acc;
  __syncthreads();
  if (t == 0) atomicAdd(loss_acc, wsum[0] + wsum[1] + wsum[2] + wsum[3]);
}

__global__ void k4_loss(const float* __restrict__ loss_acc, float* __restrict__ out)
{
  if (threadIdx.x == 0 && blockIdx.x == 0)
    out[OUT_LOSS] = loss_acc[0] * (1.25f / 33554432.f);
}

// ---- launch --------------------------------------------------------------------
extern "C" void kernel_launch(void* const* d_in, const int* in_sizes, int n_in,
                              void* d_out, int out_size, void* d_ws, size_t ws_size,
                              hipStream_t stream) {
  const float* z  = (const float*)d_in[0];
  const float* cb = (const float*)d_in[1];
  float* out = (float*)d_out;
  char* ws = (char*)d_ws;
  unsigned short*      cb16      = (unsigned short*)(ws);                 // 1 MB
  float*               cnp       = (float*)(ws + 1048576);                // 4 KB
  int*                 idx_ws    = (int*)(ws + 1052672);                  // 256 KB
  unsigned long long*  packed_ws = (unsigned long long*)(ws + 1314816);   // 512 KB
  int*                 flaglist  = (int*)(ws + 1839104);                  // 256 KB
  unsigned long long*  pairlist  = (unsigned long long*)(ws + 2095360);   // 512 KB
  int*                 counters  = (int*)(ws + 2619648);                  // [flag, pair]
  float*               loss_acc  = (float*)(ws + 2619656);

  (void)hipFuncSetAttribute((const void*)k1_main,
        hipFuncAttributeMaxDynamicSharedMemorySize, 102400);
  (void)hipFuncSetAttribute((const void*)k3_out,
        hipFuncAttributeMaxDynamicSharedMemorySize, 65664);

  k0_prep<<<1024, 64, 0, stream>>>(cb, cb16, cnp, counters, loss_acc, idx_ws, packed_ws);
  k1_main<<<256, 512, 102400, stream>>>(z, cb16, cnp, idx_ws, flaglist, pairlist, counters);
  k2a_quad<<<1024, 256, 0, stream>>>(z, cb, pairlist, counters, idx_ws);
  k2_rescan<<<256, 256, 0, stream>>>(z, cb, flaglist, counters, packed_ws);
  k3_out<<<2048, 256, 65664, stream>>>(z, cb, idx_ws, packed_ws, out, loss_acc);
  k4_loss<<<1, 1, 0, stream>>>(loss_acc, out);
}

// Round 6
// 185.299 us; speedup vs baseline: 2.6553x; 1.8800x over previous
//
#include <hip/hip_runtime.h>
#include <hip/hip_bf16.h>

// VQ-VAE vector quantizer, MI355X. z:(16,512,64,64) f32, codebook:(1024,512) f32.
// d_out f32: z_q (33554432), loss (1), idx (65536).

typedef _Float16 h8 __attribute__((ext_vector_type(8)));
typedef float f32x16 __attribute__((ext_vector_type(16)));

#define OUT_LOSS  33554432
#define OUT_IDX   33554433
#define MARGIN_T  0.15f     // ~13 sigma of fp16-dot noise on the t-gap

__device__ __forceinline__ void gload_lds16(const void* g, void* l) {
  __builtin_amdgcn_global_load_lds(
      (const __attribute__((address_space(1))) void*)g,
      (__attribute__((address_space(3))) void*)l, 16, 0, 0);
}

// ---- K0: cb fp32->fp16, fold-ordered 0.5||c||^2 table, workspace init ---------
__global__ __launch_bounds__(64) void k0_prep(
    const float* __restrict__ cb, unsigned short* __restrict__ cb16,
    float* __restrict__ cnp, int* __restrict__ counters, float* __restrict__ loss_acc,
    int* __restrict__ idx_ws, unsigned long long* __restrict__ packed_ws)
{
  const int r = blockIdx.x, l = threadIdx.x;
  const float* row = cb + (size_t)r * 512;
  float4 a  = *(const float4*)(row + l * 8);
  float4 b4 = *(const float4*)(row + l * 8 + 4);
  h8 hv;
  hv[0] = (_Float16)a.x;  hv[1] = (_Float16)a.y;  hv[2] = (_Float16)a.z;  hv[3] = (_Float16)a.w;
  hv[4] = (_Float16)b4.x; hv[5] = (_Float16)b4.y; hv[6] = (_Float16)b4.z; hv[7] = (_Float16)b4.w;
  *reinterpret_cast<h8*>(cb16 + (size_t)r * 512 + l * 8) = hv;
  float s = a.x*a.x + a.y*a.y + a.z*a.z + a.w*a.w
          + b4.x*b4.x + b4.y*b4.y + b4.z*b4.z + b4.w*b4.w;
  #pragma unroll
  for (int off = 1; off < 64; off <<= 1) s += __shfl_xor(s, off);
  if (l == 0) {
    // store 0.5*||c||^2 at the fold-order slot: [ch][khalf][reg]
    int jr = r & 31, ch = r >> 5;
    int khalf = (jr >> 2) & 1;
    int pat = jr - (khalf << 2);
    int rr  = (pat & 3) + ((pat >> 3) << 2);
    cnp[(ch << 5) + (khalf << 4) + rr] = 0.5f * s;
  }
  const int pix = (r << 6) + l;                // 1024x64 == 65536
  idx_ws[pix] = (int)0x80000000;
  packed_ws[pix] = ~0ull;
  if (r == 0 && l == 0) { counters[0] = 0; counters[1] = 0; *loss_acc = 0.f; }
}

// ---- K1: fp16 MFMA scan, 8 waves, triple-buffer + counted vmcnt, top-4 --------
// 512 thr, 256 px/block, 256 blocks (1/CU). dynLDS = 3*32768 + 4096 = 102400.
__global__ __launch_bounds__(512, 2) void k1_main(
    const float* __restrict__ z, const unsigned short* __restrict__ cb16,
    const float* __restrict__ cnp,
    int* __restrict__ idx_ws, int* __restrict__ flaglist,
    unsigned long long* __restrict__ pairlist, int* __restrict__ counters)
{
  extern __shared__ char smem[];
  float* cn_lds = reinterpret_cast<float*>(smem + 98304);
  const int tid   = threadIdx.x;
  const int lane  = tid & 63;
  const int wave  = tid >> 6;          // 0..7
  const int pxl   = lane & 31;
  const int khalf = lane >> 5;
  const int px0   = blockIdx.x << 8;   // 256 px/block
  const int b     = px0 >> 12;
  const int hw0   = px0 & 4095;
  const int laneoff = pxl * 1024 + khalf * 16;   // bytes within a 32-row chunk

  // prologue: stage chunk 0 into buf0 (transposed via source swizzle)
  {
    const char* src = reinterpret_cast<const char*>(cb16) + laneoff;
    #pragma unroll
    for (int i = 0; i < 4; ++i) {
      int slab = (wave << 2) + i;
      gload_lds16(src + slab * 32, smem + slab * 1024);
    }
  }

  // B-fragments straight from global: 32 px/wave x K=512 fp16 in VGPRs
  h8 bfrag[32];
  {
    const float* zl = z + ((size_t)(b * 512 + khalf * 8)) * 4096 + hw0 + (wave << 5) + pxl;
    #pragma unroll
    for (int s = 0; s < 32; ++s) {
      const float* zs = zl + (size_t)s * 16 * 4096;
      h8 hv;
      #pragma unroll
      for (int e = 0; e < 8; ++e) hv[e] = (_Float16)zs[(size_t)e * 4096];
      bfrag[s] = hv;
    }
  }
  for (int i = tid; i < 1024; i += 512) cn_lds[i] = cnp[i];
  __syncthreads();   // prologue drain

  float v0 = INFINITY, v1 = INFINITY, v2 = INFINITY, v3 = INFINITY;
  int   i0 = 0, i1 = 0, i2 = 0, i3 = 0;

  for (int ch = 0; ch < 32; ++ch) {
    const char* cbuf = smem + (ch % 3) * 32768;
    if (ch < 31) {
      char* dbuf = smem + ((ch + 1) % 3) * 32768;
      const char* src = reinterpret_cast<const char*>(cb16) + ((ch + 1) << 15) + laneoff;
      #pragma unroll
      for (int i = 0; i < 4; ++i) {
        int slab = (wave << 2) + i;
        gload_lds16(src + slab * 32, dbuf + slab * 1024);
      }
      asm volatile("s_waitcnt vmcnt(4)" ::: "memory");
    } else {
      asm volatile("s_waitcnt vmcnt(0)" ::: "memory");
    }
    __builtin_amdgcn_s_barrier();

    f32x16 acca, accb;
    #pragma unroll
    for (int i = 0; i < 16; ++i) { acca[i] = 0.f; accb[i] = 0.f; }
    {
      const char* ab = cbuf + (pxl << 4) + (khalf << 9);
      #pragma unroll
      for (int s = 0; s < 16; ++s) {
        h8 a0 = *reinterpret_cast<const h8*>(ab + (s << 10));
        h8 a1 = *reinterpret_cast<const h8*>(ab + ((s + 16) << 10));
        acca = __builtin_amdgcn_mfma_f32_32x32x16_f16(a0, bfrag[s],      acca, 0, 0, 0);
        accb = __builtin_amdgcn_mfma_f32_32x32x16_f16(a1, bfrag[s + 16], accb, 0, 0, 0);
      }
    }
    const float* cl = cn_lds + (ch << 5) + (khalf << 4);
    float4 q0 = *(const float4*)(cl);     float4 q1 = *(const float4*)(cl + 4);
    float4 q2 = *(const float4*)(cl + 8); float4 q3 = *(const float4*)(cl + 12);
    const float cn[16] = {q0.x,q0.y,q0.z,q0.w, q1.x,q1.y,q1.z,q1.w,
                          q2.x,q2.y,q2.z,q2.w, q3.x,q3.y,q3.z,q3.w};
    const int jbase = (ch << 5) + (khalf << 2);
    #pragma unroll
    for (int r = 0; r < 16; ++r) {
      int j = jbase + ((r & 3) + ((r >> 2) << 3));
      float sc = cn[r] - (acca[r] + accb[r]);   // 0.5||c||^2 - z.c
      if (sc <= v3) {            // top-4 insert (ties at boundary droppable: safe)
        if (sc < v0)      { v3=v2;i3=i2; v2=v1;i2=i1; v1=v0;i1=i0; v0=sc;i0=j; }
        else if (sc < v1) { v3=v2;i3=i2; v2=v1;i2=i1; v1=sc;i1=j; }
        else if (sc < v2) { v3=v2;i3=i2; v2=sc;i2=j; }
        else              { v3=sc;i3=j; }
      }
    }
  }

  // merge khalf halves: SNAPSHOT the partner's full list BEFORE mutating ours
  // (previous version interleaved shfl with insertion -> read partner's list
  //  mid-merge -> duplicated candidates -> v1==v0 -> spurious full-rescan flags)
  {
    float ow0 = __shfl_xor(v0, 32), ow1 = __shfl_xor(v1, 32),
          ow2 = __shfl_xor(v2, 32), ow3 = __shfl_xor(v3, 32);
    int   oj0 = __shfl_xor(i0, 32), oj1 = __shfl_xor(i1, 32),
          oj2 = __shfl_xor(i2, 32), oj3 = __shfl_xor(i3, 32);
    const float ow[4] = {ow0, ow1, ow2, ow3};
    const int   oj[4] = {oj0, oj1, oj2, oj3};
    #pragma unroll
    for (int k = 0; k < 4; ++k) {
      float ov = ow[k]; int oi = oj[k];
      if (ov <= v3) {
        if (ov < v0)      { v3=v2;i3=i2; v2=v1;i2=i1; v1=v0;i1=i0; v0=ov;i0=oi; }
        else if (ov < v1) { v3=v2;i3=i2; v2=v1;i2=i1; v1=ov;i1=oi; }
        else if (ov < v2) { v3=v2;i3=i2; v2=ov;i2=oi; }
        else              { v3=ov;i3=oi; }
      }
    }
  }

  const int pix = px0 + (wave << 5) + lane;   // valid for lane<32 only
  bool sane = (v0 == v0) && (v3 == v3) && ((unsigned)i0 < 1024u);
  bool unfl = sane && (v1 - v0 >= MARGIN_T);
  bool quad = sane && !unfl && (v3 - v0 >= MARGIN_T);
  bool qpred = (lane < 32) && quad;
  bool fpred = (lane < 32) && !unfl && !quad;
  if (lane < 32) idx_ws[pix] = unfl ? i0 : (int)0x80000000;

  unsigned long long qm = __ballot(qpred);
  if (qm) {
    int leader = __ffsll(qm) - 1;
    int base = 0;
    if (lane == leader) base = atomicAdd(&counters[1], __popcll(qm));
    base = __shfl(base, leader);
    if (qpred) {
      int pos = __popcll(qm & ((1ull << lane) - 1ull));
      pairlist[base + pos] = (unsigned long long)(unsigned)pix
          | ((unsigned long long)(unsigned)i0 << 16)
          | ((unsigned long long)(unsigned)i1 << 26)
          | ((unsigned long long)(unsigned)i2 << 36)
          | ((unsigned long long)(unsigned)i3 << 46);
    }
  }
  unsigned long long fm = __ballot(fpred);
  if (fm) {
    int leader = __ffsll(fm) - 1;
    int base = 0;
    if (lane == leader) base = atomicAdd(&counters[0], __popcll(fm));
    base = __shfl(base, leader);
    if (fpred) {
      int pos = __popcll(fm & ((1ull << lane) - 1ull));
      flaglist[base + pos] = pix;
    }
  }
}

// ---- K2a: exact fp64 check of <=4 candidates, one wave per pixel --------------
__global__ __launch_bounds__(256) void k2a_quad(
    const float* __restrict__ z, const float* __restrict__ cb,
    const unsigned long long* __restrict__ pairlist, const int* __restrict__ counters,
    int* __restrict__ idx_ws)
{
  const int lane = threadIdx.x & 63;
  const int wid  = (blockIdx.x << 2) + (threadIdx.x >> 6);
  const int nwav = gridDim.x << 2;
  const int nf   = counters[1];
  for (int e = wid; e < nf; e += nwav) {
    unsigned long long pk = pairlist[e];
    int pix = (int)(pk & 0xFFFFull);
    int c0 = (int)((pk >> 16) & 1023ull), c1 = (int)((pk >> 26) & 1023ull);
    int c2 = (int)((pk >> 36) & 1023ull), c3 = (int)((pk >> 46) & 1023ull);
    const float* zp = z + (size_t)(pix >> 12) * 512 * 4096 + (pix & 4095);
    double s0 = 0, s1 = 0, s2 = 0, s3 = 0;
    #pragma unroll
    for (int k = 0; k < 8; ++k) {
      int c = lane + (k << 6);
      double zv2 = 2.0 * (double)zp[(size_t)c * 4096];
      double a;
      a = (double)cb[(size_t)c0 * 512 + c]; s0 = fma(a, a - zv2, s0);
      a = (double)cb[(size_t)c1 * 512 + c]; s1 = fma(a, a - zv2, s1);
      a = (double)cb[(size_t)c2 * 512 + c]; s2 = fma(a, a - zv2, s2);
      a = (double)cb[(size_t)c3 * 512 + c]; s3 = fma(a, a - zv2, s3);
    }
    #pragma unroll
    for (int off = 32; off > 0; off >>= 1) {
      s0 += __shfl_xor(s0, off); s1 += __shfl_xor(s1, off);
      s2 += __shfl_xor(s2, off); s3 += __shfl_xor(s3, off);
    }
    double bv = s0; int bi = c0;
    if (s1 < bv || (s1 == bv && c1 < bi)) { bv = s1; bi = c1; }
    if (s2 < bv || (s2 == bv && c2 < bi)) { bv = s2; bi = c2; }
    if (s3 < bv || (s3 == bv && c3 < bi)) { bv = s3; bi = c3; }
    if (lane == 0) idx_ws[pix] = bi;
  }
}

// ---- K2b: exact fp64 full re-rank (rare: >=4 codes within margin) -------------
__global__ __launch_bounds__(256) void k2_rescan(
    const float* __restrict__ z, const float* __restrict__ cb,
    const int* __restrict__ flaglist, const int* __restrict__ counters,
    unsigned long long* __restrict__ packed_ws)
{
  __shared__ float zb[16][512];
  __shared__ unsigned long long best[16];
  __shared__ int pixl[16];
  const int t = threadIdx.x;
  const int nflag = counters[0];
  const int ntasks = ((nflag + 15) >> 4) << 2;
  for (int task = blockIdx.x; task < ntasks; task += gridDim.x) {
    const int g = task >> 2, q = task & 3;
    int rem = nflag - (g << 4);
    const int npx = rem < 16 ? rem : 16;
    if (t < 16) {
      best[t] = ~0ull;
      pixl[t] = (t < npx) ? flaglist[(g << 4) + t] : 0;
    }
    __syncthreads();
    for (int i = t; i < (npx << 9); i += 256) {
      int p = i >> 9, c = i & 511;
      int pix = pixl[p];
      zb[p][c] = z[((size_t)(pix >> 12) * 512 + c) * 4096 + (pix & 4095)];
    }
    __syncthreads();
    const int j = (q << 8) + t;
    const float* row = cb + (size_t)j * 512;
    double dot[16];
    #pragma unroll
    for (int p = 0; p < 16; ++p) dot[p] = 0.0;
    double cn = 0.0;
    for (int k = 0; k < 512; k += 4) {
      float4 cv = *(const float4*)(row + k);
      double c0 = cv.x, c1 = cv.y, c2 = cv.z, c3 = cv.w;
      cn = fma(c0, c0, cn); cn = fma(c1, c1, cn);
      cn = fma(c2, c2, cn); cn = fma(c3, c3, cn);
      #pragma unroll
      for (int p = 0; p < 16; ++p) {
        dot[p] = fma(c0, (double)zb[p][k + 0], dot[p]);
        dot[p] = fma(c1, (double)zb[p][k + 1], dot[p]);
        dot[p] = fma(c2, (double)zb[p][k + 2], dot[p]);
        dot[p] = fma(c3, (double)zb[p][k + 3], dot[p]);
      }
    }
    #pragma unroll
    for (int p = 0; p < 16; ++p) {
      if (p < npx) {
        double d = fma(-2.0, dot[p], cn);
        unsigned long long u = (unsigned long long)__double_as_longlong(d);
        u = (u >> 63) ? ~u : (u | 0x8000000000000000ull);
        unsigned long long pkk = (u & ~1023ull) | (unsigned long long)j;
        atomicMin(&best[p], pkk);
      }
    }
    __syncthreads();
    if (t < npx) atomicMin(&packed_ws[pixl[t]], best[t]);
    __syncthreads();
  }
}

// ---- K3: gather + transpose-write z_q (f32), idx (f32), loss ------------------
__global__ __launch_bounds__(256) void k3_out(
    const float* __restrict__ z, const float* __restrict__ cb,
    const int* __restrict__ idx_ws, const unsigned long long* __restrict__ packed_ws,
    float* __restrict__ out, float* __restrict__ loss_acc)
{
  extern __shared__ float rows[];         // [32][513]
  __shared__ int idxs[32];
  __shared__ float wsum[4];
  const int t = threadIdx.x;
  const int pix0 = blockIdx.x << 5;       // 32 px/block
  const int b = pix0 >> 12, hw0 = pix0 & 4095;
  if (t < 32) {
    int pix = pix0 + t;
    int v = idx_ws[pix];
    unsigned j = (v < 0) ? (unsigned)(packed_ws[pix] & 1023ull) : (unsigned)v;
    j &= 1023u;
    idxs[t] = (int)j;
    out[OUT_IDX + pix] = (float)j;
  }
  __syncthreads();
  for (int i = t; i < 32 * 128; i += 256) {
    int r = i >> 7, kq = (i & 127) << 2;
    float4 v = *(const float4*)(cb + (size_t)idxs[r] * 512 + kq);
    float* dst = rows + r * 513 + kq;
    dst[0] = v.x; dst[1] = v.y; dst[2] = v.z; dst[3] = v.w;
  }
  __syncthreads();
  const int pl = (t & 7) << 2;   // pixel quad {0,4,...,28}
  const int cg = t >> 3;         // 0..31
  float acc = 0.f;
  for (int c0 = 0; c0 < 512; c0 += 32) {
    int c = c0 + cg;
    size_t go = ((size_t)(b * 512 + c)) * 4096 + hw0 + pl;
    float4 zv = *(const float4*)(z + go);
    float q0 = rows[(pl + 0) * 513 + c], q1 = rows[(pl + 1) * 513 + c];
    float q2 = rows[(pl + 2) * 513 + c], q3 = rows[(pl + 3) * 513 + c];
    float d0 = q0 - zv.x, d1 = q1 - zv.y, d2 = q2 - zv.z, d3 = q3 - zv.w;
    acc = fmaf(d0, d0, acc); acc = fmaf(d1, d1, acc);
    acc = fmaf(d2, d2, acc); acc = fmaf(d3, d3, acc);
    float4 qv;
    qv.x = zv.x + d0; qv.y = zv.y + d1;    // mimic ref: zp + (z_q - zp)
    qv.z = zv.z + d2; qv.w = zv.w + d3;
    *reinterpret_cast<float4*>(out + go) = qv;
  }
  #pragma unroll
  for (int off = 32; off > 0; off >>= 1) acc += __shfl_down(acc, off);
  if ((t & 63) == 0) wsum[t >> 6] = acc;
  __syncthreads();
  if (t == 0) atomicAdd(loss_acc, wsum[0] + wsum[1] + wsum[2] + wsum[3]);
}

__global__ void k4_loss(const float* __restrict__ loss_acc, float* __restrict__ out)
{
  if (threadIdx.x == 0 && blockIdx.x == 0)
    out[OUT_LOSS] = loss_acc[0] * (1.25f / 33554432.f);
}

// ---- launch --------------------------------------------------------------------
extern "C" void kernel_launch(void* const* d_in, const int* in_sizes, int n_in,
                              void* d_out, int out_size, void* d_ws, size_t ws_size,
                              hipStream_t stream) {
  const float* z  = (const float*)d_in[0];
  const float* cb = (const float*)d_in[1];
  float* out = (float*)d_out;
  char* ws = (char*)d_ws;
  unsigned short*      cb16      = (unsigned short*)(ws);                 // 1 MB
  float*               cnp       = (float*)(ws + 1048576);                // 4 KB
  int*                 idx_ws    = (int*)(ws + 1052672);                  // 256 KB
  unsigned long long*  packed_ws = (unsigned long long*)(ws + 1314816);   // 512 KB
  int*                 flaglist  = (int*)(ws + 1839104);                  // 256 KB
  unsigned long long*  pairlist  = (unsigned long long*)(ws + 2095360);   // 512 KB
  int*                 counters  = (int*)(ws + 2619648);                  // [flag, pair]
  float*               loss_acc  = (float*)(ws + 2619656);

  (void)hipFuncSetAttribute((const void*)k1_main,
        hipFuncAttributeMaxDynamicSharedMemorySize, 102400);
  (void)hipFuncSetAttribute((const void*)k3_out,
        hipFuncAttributeMaxDynamicSharedMemorySize, 65664);

  k0_prep<<<1024, 64, 0, stream>>>(cb, cb16, cnp, counters, loss_acc, idx_ws, packed_ws);
  k1_main<<<256, 512, 102400, stream>>>(z, cb16, cnp, idx_ws, flaglist, pairlist, counters);
  k2a_quad<<<1024, 256, 0, stream>>>(z, cb, pairlist, counters, idx_ws);
  k2_rescan<<<256, 256, 0, stream>>>(z, cb, flaglist, counters, packed_ws);
  k3_out<<<2048, 256, 65664, stream>>>(z, cb, idx_ws, packed_ws, out, loss_acc);
  k4_loss<<<1, 1, 0, stream>>>(loss_acc, out);
}

// Round 7
// 183.914 us; speedup vs baseline: 2.6753x; 1.0075x over previous
//
#include <hip/hip_runtime.h>
#include <hip/hip_bf16.h>

// VQ-VAE vector quantizer, MI355X. z:(16,512,64,64) f32, codebook:(1024,512) f32.
// d_out f32: z_q (33554432), loss (1), idx (65536).

typedef _Float16 h8 __attribute__((ext_vector_type(8)));
typedef float f32x16 __attribute__((ext_vector_type(16)));

#define OUT_LOSS  33554432
#define OUT_IDX   33554433
#define MARGIN_T  0.15f     // ~13 sigma of fp16-dot noise on the t-gap

__device__ __forceinline__ void gload_lds16(const void* g, void* l) {
  __builtin_amdgcn_global_load_lds(
      (const __attribute__((address_space(1))) void*)g,
      (__attribute__((address_space(3))) void*)l, 16, 0, 0);
}

// ---- K0: cb fp32->fp16, fold-ordered 0.5||c||^2 table, workspace init ---------
__global__ __launch_bounds__(64) void k0_prep(
    const float* __restrict__ cb, unsigned short* __restrict__ cb16,
    float* __restrict__ cnp, int* __restrict__ counters, float* __restrict__ loss_acc,
    int* __restrict__ idx_ws, unsigned long long* __restrict__ packed_ws)
{
  const int r = blockIdx.x, l = threadIdx.x;
  const float* row = cb + (size_t)r * 512;
  float4 a  = *(const float4*)(row + l * 8);
  float4 b4 = *(const float4*)(row + l * 8 + 4);
  h8 hv;
  hv[0] = (_Float16)a.x;  hv[1] = (_Float16)a.y;  hv[2] = (_Float16)a.z;  hv[3] = (_Float16)a.w;
  hv[4] = (_Float16)b4.x; hv[5] = (_Float16)b4.y; hv[6] = (_Float16)b4.z; hv[7] = (_Float16)b4.w;
  *reinterpret_cast<h8*>(cb16 + (size_t)r * 512 + l * 8) = hv;
  float s = a.x*a.x + a.y*a.y + a.z*a.z + a.w*a.w
          + b4.x*b4.x + b4.y*b4.y + b4.z*b4.z + b4.w*b4.w;
  #pragma unroll
  for (int off = 1; off < 64; off <<= 1) s += __shfl_xor(s, off);
  if (l == 0) {
    // store 0.5*||c||^2 at the fold-order slot: [ch][khalf][reg]
    int jr = r & 31, ch = r >> 5;
    int khalf = (jr >> 2) & 1;
    int pat = jr - (khalf << 2);
    int rr  = (pat & 3) + ((pat >> 3) << 2);
    cnp[(ch << 5) + (khalf << 4) + rr] = 0.5f * s;
  }
  const int pix = (r << 6) + l;                // 1024x64 == 65536
  idx_ws[pix] = (int)0x80000000;
  packed_ws[pix] = ~0ull;
  if (r == 0 && l == 0) { counters[0] = 0; counters[1] = 0; *loss_acc = 0.f; }
}

// ---- K1: fp16 MFMA scan, 4 waves, 2 blocks/CU, double-buffer, top-4 -----------
// 256 thr, 128 px/block, 512 blocks. dynLDS = 2*32768 + 4096 = 69632.
__global__ __launch_bounds__(256, 2) void k1_main(
    const float* __restrict__ z, const unsigned short* __restrict__ cb16,
    const float* __restrict__ cnp,
    int* __restrict__ idx_ws, int* __restrict__ flaglist,
    unsigned long long* __restrict__ pairlist, int* __restrict__ counters)
{
  extern __shared__ char smem[];
  float* cn_lds = reinterpret_cast<float*>(smem + 65536);
  const int tid   = threadIdx.x;
  const int lane  = tid & 63;
  const int wave  = tid >> 6;          // 0..3
  const int pxl   = lane & 31;
  const int khalf = lane >> 5;
  const int px0   = blockIdx.x << 7;   // 128 px/block
  const int b     = px0 >> 12;
  const int hw0   = px0 & 4095;
  const int laneoff = pxl * 1024 + khalf * 16;   // bytes within a 32-row chunk

  // prologue: stage chunk 0 into buf0 (transposed via source swizzle)
  {
    const char* src = reinterpret_cast<const char*>(cb16) + laneoff;
    #pragma unroll
    for (int i = 0; i < 8; ++i) {
      int slab = (wave << 3) + i;      // 0..31
      gload_lds16(src + slab * 32, smem + slab * 1024);
    }
  }

  // B-fragments straight from global: 32 px/wave x K=512 fp16 in VGPRs
  h8 bfrag[32];
  {
    const float* zl = z + ((size_t)(b * 512 + khalf * 8)) * 4096 + hw0 + (wave << 5) + pxl;
    #pragma unroll
    for (int s = 0; s < 32; ++s) {
      const float* zs = zl + (size_t)s * 16 * 4096;
      h8 hv;
      #pragma unroll
      for (int e = 0; e < 8; ++e) hv[e] = (_Float16)zs[(size_t)e * 4096];
      bfrag[s] = hv;
    }
  }
  for (int i = tid; i < 1024; i += 256) cn_lds[i] = cnp[i];
  __syncthreads();   // chunk0 staged (syncthreads drains vmcnt+lgkmcnt)

  float v0 = INFINITY, v1 = INFINITY, v2 = INFINITY, v3 = INFINITY;
  int   i0 = 0, i1 = 0, i2 = 0, i3 = 0;

  for (int ch = 0; ch < 32; ++ch) {
    const char* cbuf = smem + ((ch & 1) << 15);
    if (ch) {
      asm volatile("s_waitcnt vmcnt(0)" ::: "memory");  // my 8 loads for ch landed
      __builtin_amdgcn_s_barrier();                     // everyone's landed; ch-1 compute done
    }
    if (ch < 31) {   // prefetch ch+1 into the other buffer (overlaps compute ch)
      char* dbuf = smem + (((ch & 1) ^ 1) << 15);
      const char* src = reinterpret_cast<const char*>(cb16) + ((ch + 1) << 15) + laneoff;
      #pragma unroll
      for (int i = 0; i < 8; ++i) {
        int slab = (wave << 3) + i;
        gload_lds16(src + slab * 32, dbuf + slab * 1024);
      }
    }

    f32x16 acca, accb;
    #pragma unroll
    for (int i = 0; i < 16; ++i) { acca[i] = 0.f; accb[i] = 0.f; }
    {
      const char* ab = cbuf + (pxl << 4) + (khalf << 9);
      #pragma unroll
      for (int s = 0; s < 16; ++s) {
        h8 a0 = *reinterpret_cast<const h8*>(ab + (s << 10));
        h8 a1 = *reinterpret_cast<const h8*>(ab + ((s + 16) << 10));
        acca = __builtin_amdgcn_mfma_f32_32x32x16_f16(a0, bfrag[s],      acca, 0, 0, 0);
        accb = __builtin_amdgcn_mfma_f32_32x32x16_f16(a1, bfrag[s + 16], accb, 0, 0, 0);
      }
    }
    const float* cl = cn_lds + (ch << 5) + (khalf << 4);
    float4 q0 = *(const float4*)(cl);     float4 q1 = *(const float4*)(cl + 4);
    float4 q2 = *(const float4*)(cl + 8); float4 q3 = *(const float4*)(cl + 12);
    const float cn[16] = {q0.x,q0.y,q0.z,q0.w, q1.x,q1.y,q1.z,q1.w,
                          q2.x,q2.y,q2.z,q2.w, q3.x,q3.y,q3.z,q3.w};
    const int jbase = (ch << 5) + (khalf << 2);
    #pragma unroll
    for (int r = 0; r < 16; ++r) {
      int j = jbase + ((r & 3) + ((r >> 2) << 3));
      float sc = cn[r] - (acca[r] + accb[r]);   // 0.5||c||^2 - z.c
      if (__ballot(sc < v3)) {                  // wave-uniform skip when no lane inserts
        // branchless top-4 insert (strict <; boundary ties dropped -> safe,
        // interior near-ties resolve via the exact fp64 paths)
        bool c0 = sc < v0, c1 = sc < v1, c2 = sc < v2, c3 = sc < v3;
        v3 = c2 ? v2 : (c3 ? sc : v3);  i3 = c2 ? i2 : (c3 ? j : i3);
        v2 = c1 ? v1 : (c2 ? sc : v2);  i2 = c1 ? i1 : (c2 ? j : i2);
        v1 = c0 ? v0 : (c1 ? sc : v1);  i1 = c0 ? i0 : (c1 ? j : i1);
        v0 = c0 ? sc : v0;              i0 = c0 ? j  : i0;
      }
    }
  }

  // merge khalf halves: snapshot partner's full list BEFORE mutating ours
  {
    float ow0 = __shfl_xor(v0, 32), ow1 = __shfl_xor(v1, 32),
          ow2 = __shfl_xor(v2, 32), ow3 = __shfl_xor(v3, 32);
    int   oj0 = __shfl_xor(i0, 32), oj1 = __shfl_xor(i1, 32),
          oj2 = __shfl_xor(i2, 32), oj3 = __shfl_xor(i3, 32);
    const float ow[4] = {ow0, ow1, ow2, ow3};
    const int   oj[4] = {oj0, oj1, oj2, oj3};
    #pragma unroll
    for (int k = 0; k < 4; ++k) {
      float ov = ow[k]; int oi = oj[k];
      bool c0 = ov < v0, c1 = ov < v1, c2 = ov < v2, c3 = ov < v3;
      v3 = c2 ? v2 : (c3 ? ov : v3);  i3 = c2 ? i2 : (c3 ? oi : i3);
      v2 = c1 ? v1 : (c2 ? ov : v2);  i2 = c1 ? i1 : (c2 ? oi : i2);
      v1 = c0 ? v0 : (c1 ? ov : v1);  i1 = c0 ? i0 : (c1 ? oi : i1);
      v0 = c0 ? ov : v0;              i0 = c0 ? oi : i0;
    }
  }

  const int pix = px0 + (wave << 5) + lane;   // valid for lane<32 only
  bool sane = (v0 == v0) && (v3 == v3) && ((unsigned)i0 < 1024u);
  bool unfl = sane && (v1 - v0 >= MARGIN_T);
  bool quad = sane && !unfl && (v3 - v0 >= MARGIN_T);
  bool qpred = (lane < 32) && quad;
  bool fpred = (lane < 32) && !unfl && !quad;
  if (lane < 32) idx_ws[pix] = unfl ? i0 : (int)0x80000000;

  unsigned long long qm = __ballot(qpred);
  if (qm) {
    int leader = __ffsll(qm) - 1;
    int base = 0;
    if (lane == leader) base = atomicAdd(&counters[1], __popcll(qm));
    base = __shfl(base, leader);
    if (qpred) {
      int pos = __popcll(qm & ((1ull << lane) - 1ull));
      pairlist[base + pos] = (unsigned long long)(unsigned)pix
          | ((unsigned long long)(unsigned)i0 << 16)
          | ((unsigned long long)(unsigned)i1 << 26)
          | ((unsigned long long)(unsigned)i2 << 36)
          | ((unsigned long long)(unsigned)i3 << 46);
    }
  }
  unsigned long long fm = __ballot(fpred);
  if (fm) {
    int leader = __ffsll(fm) - 1;
    int base = 0;
    if (lane == leader) base = atomicAdd(&counters[0], __popcll(fm));
    base = __shfl(base, leader);
    if (fpred) {
      int pos = __popcll(fm & ((1ull << lane) - 1ull));
      flaglist[base + pos] = pix;
    }
  }
}

// ---- K2a: exact fp64 check of <=4 candidates, one wave per pixel --------------
__global__ __launch_bounds__(256) void k2a_quad(
    const float* __restrict__ z, const float* __restrict__ cb,
    const unsigned long long* __restrict__ pairlist, const int* __restrict__ counters,
    int* __restrict__ idx_ws)
{
  const int lane = threadIdx.x & 63;
  const int wid  = (blockIdx.x << 2) + (threadIdx.x >> 6);
  const int nwav = gridDim.x << 2;
  const int nf   = counters[1];
  for (int e = wid; e < nf; e += nwav) {
    unsigned long long pk = pairlist[e];
    int pix = (int)(pk & 0xFFFFull);
    int c0 = (int)((pk >> 16) & 1023ull), c1 = (int)((pk >> 26) & 1023ull);
    int c2 = (int)((pk >> 36) & 1023ull), c3 = (int)((pk >> 46) & 1023ull);
    const float* zp = z + (size_t)(pix >> 12) * 512 * 4096 + (pix & 4095);
    double s0 = 0, s1 = 0, s2 = 0, s3 = 0;
    #pragma unroll
    for (int k = 0; k < 8; ++k) {
      int c = lane + (k << 6);
      double zv2 = 2.0 * (double)zp[(size_t)c * 4096];
      double a;
      a = (double)cb[(size_t)c0 * 512 + c]; s0 = fma(a, a - zv2, s0);
      a = (double)cb[(size_t)c1 * 512 + c]; s1 = fma(a, a - zv2, s1);
      a = (double)cb[(size_t)c2 * 512 + c]; s2 = fma(a, a - zv2, s2);
      a = (double)cb[(size_t)c3 * 512 + c]; s3 = fma(a, a - zv2, s3);
    }
    #pragma unroll
    for (int off = 32; off > 0; off >>= 1) {
      s0 += __shfl_xor(s0, off); s1 += __shfl_xor(s1, off);
      s2 += __shfl_xor(s2, off); s3 += __shfl_xor(s3, off);
    }
    double bv = s0; int bi = c0;
    if (s1 < bv || (s1 == bv && c1 < bi)) { bv = s1; bi = c1; }
    if (s2 < bv || (s2 == bv && c2 < bi)) { bv = s2; bi = c2; }
    if (s3 < bv || (s3 == bv && c3 < bi)) { bv = s3; bi = c3; }
    if (lane == 0) idx_ws[pix] = bi;
  }
}

// ---- K2b: exact fp64 full re-rank (rare: >=4 codes within margin) -------------
__global__ __launch_bounds__(256) void k2_rescan(
    const float* __restrict__ z, const float* __restrict__ cb,
    const int* __restrict__ flaglist, const int* __restrict__ counters,
    unsigned long long* __restrict__ packed_ws)
{
  __shared__ float zb[16][512];
  __shared__ unsigned long long best[16];
  __shared__ int pixl[16];
  const int t = threadIdx.x;
  const int nflag = counters[0];
  const int ntasks = ((nflag + 15) >> 4) << 2;
  for (int task = blockIdx.x; task < ntasks; task += gridDim.x) {
    const int g = task >> 2, q = task & 3;
    int rem = nflag - (g << 4);
    const int npx = rem < 16 ? rem : 16;
    if (t < 16) {
      best[t] = ~0ull;
      pixl[t] = (t < npx) ? flaglist[(g << 4) + t] : 0;
    }
    __syncthreads();
    for (int i = t; i < (npx << 9); i += 256) {
      int p = i >> 9, c = i & 511;
      int pix = pixl[p];
      zb[p][c] = z[((size_t)(pix >> 12) * 512 + c) * 4096 + (pix & 4095)];
    }
    __syncthreads();
    const int j = (q << 8) + t;
    const float* row = cb + (size_t)j * 512;
    double dot[16];
    #pragma unroll
    for (int p = 0; p < 16; ++p) dot[p] = 0.0;
    double cn = 0.0;
    for (int k = 0; k < 512; k += 4) {
      float4 cv = *(const float4*)(row + k);
      double c0 = cv.x, c1 = cv.y, c2 = cv.z, c3 = cv.w;
      cn = fma(c0, c0, cn); cn = fma(c1, c1, cn);
      cn = fma(c2, c2, cn); cn = fma(c3, c3, cn);
      #pragma unroll
      for (int p = 0; p < 16; ++p) {
        dot[p] = fma(c0, (double)zb[p][k + 0], dot[p]);
        dot[p] = fma(c1, (double)zb[p][k + 1], dot[p]);
        dot[p] = fma(c2, (double)zb[p][k + 2], dot[p]);
        dot[p] = fma(c3, (double)zb[p][k + 3], dot[p]);
      }
    }
    #pragma unroll
    for (int p = 0; p < 16; ++p) {
      if (p < npx) {
        double d = fma(-2.0, dot[p], cn);
        unsigned long long u = (unsigned long long)__double_as_longlong(d);
        u = (u >> 63) ? ~u : (u | 0x8000000000000000ull);
        unsigned long long pkk = (u & ~1023ull) | (unsigned long long)j;
        atomicMin(&best[p], pkk);
      }
    }
    __syncthreads();
    if (t < npx) atomicMin(&packed_ws[pixl[t]], best[t]);
    __syncthreads();
  }
}

// ---- K3: gather + transpose-write z_q (f32), idx (f32), loss ------------------
__global__ __launch_bounds__(256) void k3_out(
    const float* __restrict__ z, const float* __restrict__ cb,
    const int* __restrict__ idx_ws, const unsigned long long* __restrict__ packed_ws,
    float* __restrict__ out, float* __restrict__ loss_acc)
{
  extern __shared__ float rows[];         // [32][513]
  __shared__ int idxs[32];
  __shared__ float wsum[4];
  const int t = threadIdx.x;
  const int pix0 = blockIdx.x << 5;       // 32 px/block
  const int b = pix0 >> 12, hw0 = pix0 & 4095;
  if (t < 32) {
    int pix = pix0 + t;
    int v = idx_ws[pix];
    unsigned j = (v < 0) ? (unsigned)(packed_ws[pix] & 1023ull) : (unsigned)v;
    j &= 1023u;
    idxs[t] = (int)j;
    out[OUT_IDX + pix] = (float)j;
  }
  __syncthreads();
  for (int i = t; i < 32 * 128; i += 256) {
    int r = i >> 7, kq = (i & 127) << 2;
    float4 v = *(const float4*)(cb + (size_t)idxs[r] * 512 + kq);
    float* dst = rows + r * 513 + kq;
    dst[0] = v.x; dst[1] = v.y; dst[2] = v.z; dst[3] = v.w;
  }
  __syncthreads();
  const int pl = (t & 7) << 2;   // pixel quad {0,4,...,28}
  const int cg = t >> 3;         // 0..31
  float acc = 0.f;
  for (int c0 = 0; c0 < 512; c0 += 32) {
    int c = c0 + cg;
    size_t go = ((size_t)(b * 512 + c)) * 4096 + hw0 + pl;
    float4 zv = *(const float4*)(z + go);
    float q0 = rows[(pl + 0) * 513 + c], q1 = rows[(pl + 1) * 513 + c];
    float q2 = rows[(pl + 2) * 513 + c], q3 = rows[(pl + 3) * 513 + c];
    float d0 = q0 - zv.x, d1 = q1 - zv.y, d2 = q2 - zv.z, d3 = q3 - zv.w;
    acc = fmaf(d0, d0, acc); acc = fmaf(d1, d1, acc);
    acc = fmaf(d2, d2, acc); acc = fmaf(d3, d3, acc);
    float4 qv;
    qv.x = zv.x + d0; qv.y = zv.y + d1;    // mimic ref: zp + (z_q - zp)
    qv.z = zv.z + d2; qv.w = zv.w + d3;
    *reinterpret_cast<float4*>(out + go) = qv;
  }
  #pragma unroll
  for (int off = 32; off > 0; off >>= 1) acc += __shfl_down(acc, off);
  if ((t & 63) == 0) wsum[t >> 6] = acc;
  __syncthreads();
  if (t == 0) atomicAdd(loss_acc, wsum[0] + wsum[1] + wsum[2] + wsum[3]);
}

__global__ void k4_loss(const float* __restrict__ loss_acc, float* __restrict__ out)
{
  if (threadIdx.x == 0 && blockIdx.x == 0)
    out[OUT_LOSS] = loss_acc[0] * (1.25f / 33554432.f);
}

// ---- launch --------------------------------------------------------------------
extern "C" void kernel_launch(void* const* d_in, const int* in_sizes, int n_in,
                              void* d_out, int out_size, void* d_ws, size_t ws_size,
                              hipStream_t stream) {
  const float* z  = (const float*)d_in[0];
  const float* cb = (const float*)d_in[1];
  float* out = (float*)d_out;
  char* ws = (char*)d_ws;
  unsigned short*      cb16      = (unsigned short*)(ws);                 // 1 MB
  float*               cnp       = (float*)(ws + 1048576);                // 4 KB
  int*                 idx_ws    = (int*)(ws + 1052672);                  // 256 KB
  unsigned long long*  packed_ws = (unsigned long long*)(ws + 1314816);   // 512 KB
  int*                 flaglist  = (int*)(ws + 1839104);                  // 256 KB
  unsigned long long*  pairlist  = (unsigned long long*)(ws + 2095360);   // 512 KB
  int*                 counters  = (int*)(ws + 2619648);                  // [flag, pair]
  float*               loss_acc  = (float*)(ws + 2619656);

  (void)hipFuncSetAttribute((const void*)k1_main,
        hipFuncAttributeMaxDynamicSharedMemorySize, 69632);
  (void)hipFuncSetAttribute((const void*)k3_out,
        hipFuncAttributeMaxDynamicSharedMemorySize, 65664);

  k0_prep<<<1024, 64, 0, stream>>>(cb, cb16, cnp, counters, loss_acc, idx_ws, packed_ws);
  k1_main<<<512, 256, 69632, stream>>>(z, cb16, cnp, idx_ws, flaglist, pairlist, counters);
  k2a_quad<<<1024, 256, 0, stream>>>(z, cb, pairlist, counters, idx_ws);
  k2_rescan<<<256, 256, 0, stream>>>(z, cb, flaglist, counters, packed_ws);
  k3_out<<<2048, 256, 65664, stream>>>(z, cb, idx_ws, packed_ws, out, loss_acc);
  k4_loss<<<1, 1, 0, stream>>>(loss_acc, out);
}